// Round 7
// baseline (334.025 us; speedup 1.0000x reference)
//
#include <hip/hip_runtime.h>

#define N_DRUG 572
#define DIM 512
#define MAXDEG 32
#define MN (N_DRUG * DIM)     // 292864
#define LSTR 68               // gemm LDS stride (words)
#define FSW 9                 // scan fs stride: 8 cols + 1 pad
#define NBLK 256

struct GemmS { float As[2][32 * LSTR]; float Bs[2][32 * LSTR]; };   // 34.8 KB
struct AttnS { float sc[64]; int tails[64]; int rels[64]; };
struct ScanS {                                                       // ~62.8 KB
    float fs[(N_DRUG + 1) * FSW];        // row N_DRUG = zeros (dummy)
    float fspad[3];                      // align offs to 16B
    alignas(16) unsigned short offs[N_DRUG * MAXDEG];  // padded nbr rows, dummy=N_DRUG
    float inv[N_DRUG];                   // 0.5/deg or 0
    unsigned short mxs[N_DRUG];          // (max lower-dep)+1, 0 = none
    float part[2][32][8];
    float bnp[2][8];
    int genext[2];
    int ge0;
};
union SmemU { GemmS g; AttnS a; ScanS s; };

// agent-scope grid barrier: all NBLK blocks co-resident (grid == #CUs)
__device__ __forceinline__ void gridbar(int* cnt, int id) {
    __syncthreads();
    if (threadIdx.x == 0) {
        __hip_atomic_fetch_add(&cnt[id], 1, __ATOMIC_ACQ_REL, __HIP_MEMORY_SCOPE_AGENT);
        while (__hip_atomic_load(&cnt[id], __ATOMIC_RELAXED, __HIP_MEMORY_SCOPE_AGENT) < NBLK)
            __builtin_amdgcn_s_sleep(8);
        __builtin_amdgcn_fence(__ATOMIC_ACQUIRE, "agent");
    }
    __syncthreads();
}

// one 64x64 output tile, split-K chunk bz; 4x4 micro, double-buffered LDS
__device__ void gemm_tile(GemmS& g,
    const float* __restrict__ drugW, const int* __restrict__ drug_name,
    const float* __restrict__ agg, const float* __restrict__ B,
    float* __restrict__ C, int M, int Kc, int mode, int bx, int by, int bz)
{
    __syncthreads();   // LDS reuse guard
    const int t = threadIdx.x;
    const int tn = t & 15, tm = t >> 4;
    const int arow = t & 63, akq = (t >> 6) * 8;
    const int brow = t >> 3, bcq = (t & 7) * 8;
    const int c0 = bx * 64, r0 = by * 64;
    const int ks0 = bz * Kc;
    const int nsteps = Kc >> 5;
    const int row = r0 + arow;
    const bool aval = row < M;
    const int dn = aval ? drug_name[row] : 0;
    const float* __restrict__ drow = drugW + (size_t)dn * 512;
    const float* __restrict__ grow = agg + (size_t)row * 512;

    float av[8], bv[8];
    float acc[4][4] = {{0.f}};

    {
        const int k = ks0 + akq;
        if (aval) {
            const float* src = (mode == 1) ? ((k < 512) ? (grow + k) : (drow + (k - 512)))
                                           : (drow + k);
            const float4 x = ((const float4*)src)[0];
            const float4 y = ((const float4*)src)[1];
            av[0]=x.x; av[1]=x.y; av[2]=x.z; av[3]=x.w;
            av[4]=y.x; av[5]=y.y; av[6]=y.z; av[7]=y.w;
        } else {
            #pragma unroll
            for (int j = 0; j < 8; ++j) av[j] = 0.f;
        }
        const float* bsrc = B + (size_t)(ks0 + brow) * 512 + c0 + bcq;
        const float4 x = ((const float4*)bsrc)[0];
        const float4 y = ((const float4*)bsrc)[1];
        bv[0]=x.x; bv[1]=x.y; bv[2]=x.z; bv[3]=x.w;
        bv[4]=y.x; bv[5]=y.y; bv[6]=y.z; bv[7]=y.w;
    }
    #pragma unroll
    for (int i = 0; i < 8; ++i) g.As[0][(akq + i) * LSTR + arow] = av[i];
    *(float4*)&g.Bs[0][brow * LSTR + bcq]     = make_float4(bv[0], bv[1], bv[2], bv[3]);
    *(float4*)&g.Bs[0][brow * LSTR + bcq + 4] = make_float4(bv[4], bv[5], bv[6], bv[7]);
    __syncthreads();

    int p = 0;
    for (int s = 0; s < nsteps; ++s) {
        const bool more = (s + 1) < nsteps;
        if (more) {
            const int k = ks0 + (s + 1) * 32 + akq;
            if (aval) {
                const float* src = (mode == 1) ? ((k < 512) ? (grow + k) : (drow + (k - 512)))
                                               : (drow + k);
                const float4 x = ((const float4*)src)[0];
                const float4 y = ((const float4*)src)[1];
                av[0]=x.x; av[1]=x.y; av[2]=x.z; av[3]=x.w;
                av[4]=y.x; av[5]=y.y; av[6]=y.z; av[7]=y.w;
            }
            const float* bsrc = B + (size_t)(ks0 + (s + 1) * 32 + brow) * 512 + c0 + bcq;
            const float4 x = ((const float4*)bsrc)[0];
            const float4 y = ((const float4*)bsrc)[1];
            bv[0]=x.x; bv[1]=x.y; bv[2]=x.z; bv[3]=x.w;
            bv[4]=y.x; bv[5]=y.y; bv[6]=y.z; bv[7]=y.w;
        }
        #pragma unroll
        for (int kk = 0; kk < 32; ++kk) {
            const float4 a = *(const float4*)&g.As[p][kk * LSTR + tm * 4];
            const float4 b = *(const float4*)&g.Bs[p][kk * LSTR + tn * 4];
            const float ar[4] = {a.x, a.y, a.z, a.w};
            const float br[4] = {b.x, b.y, b.z, b.w};
            #pragma unroll
            for (int i = 0; i < 4; ++i)
                #pragma unroll
                for (int j = 0; j < 4; ++j)
                    acc[i][j] = fmaf(ar[i], br[j], acc[i][j]);
        }
        __syncthreads();
        if (more) {
            const int q2 = p ^ 1;
            #pragma unroll
            for (int i = 0; i < 8; ++i) g.As[q2][(akq + i) * LSTR + arow] = av[i];
            *(float4*)&g.Bs[q2][brow * LSTR + bcq]     = make_float4(bv[0], bv[1], bv[2], bv[3]);
            *(float4*)&g.Bs[q2][brow * LSTR + bcq + 4] = make_float4(bv[4], bv[5], bv[6], bv[7]);
            __syncthreads();
            p = q2;
        }
    }

    float* __restrict__ Cp = C + (size_t)bz * MN;
    #pragma unroll
    for (int i = 0; i < 4; ++i) {
        const int r = r0 + tm * 4 + i;
        if (r < M)
            *(float4*)&Cp[(size_t)r * 512 + c0 + tn * 4] =
                make_float4(acc[i][0], acc[i][1], acc[i][2], acc[i][3]);
    }
}

// attention for one drug n (256 threads)
__device__ void attn_one(AttnS& a,
    const float* __restrict__ relaW, const float* __restrict__ entW,
    const int* __restrict__ adj_tail, const int* __restrict__ adj_rel,
    const float* __restrict__ qb, int skq, float* __restrict__ agg, int n)
{
    const int t = threadIdx.x;
    const int lane = t & 63;
    const int w = t >> 6;
    __syncthreads();   // LDS reuse guard
    if (t < 64) { a.tails[t] = adj_tail[n * 64 + t]; a.rels[t] = adj_rel[n * 64 + t]; }

    float qv[8];
    {
        const float* qp = qb + (size_t)n * 512 + lane * 8;
        float4 x = ((const float4*)qp)[0], y = ((const float4*)qp)[1];
        qv[0]=x.x; qv[1]=x.y; qv[2]=x.z; qv[3]=x.w;
        qv[4]=y.x; qv[5]=y.y; qv[6]=y.z; qv[7]=y.w;
        for (int pt = 1; pt < skq; ++pt) {
            const float* q2 = qp + (size_t)pt * MN;
            float4 x2 = ((const float4*)q2)[0], y2 = ((const float4*)q2)[1];
            qv[0]+=x2.x; qv[1]+=x2.y; qv[2]+=x2.z; qv[3]+=x2.w;
            qv[4]+=y2.x; qv[5]+=y2.y; qv[6]+=y2.z; qv[7]+=y2.w;
        }
    }
    __syncthreads();

    #pragma unroll 4
    for (int kk = 0; kk < 16; ++kk) {
        const int k = w * 16 + kk;
        const float4* p = (const float4*)(relaW + (size_t)a.rels[k] * 512 + lane * 8);
        float4 x = p[0], y = p[1];
        float s = 0.f;
        s = fmaf(qv[0], x.x, s); s = fmaf(qv[1], x.y, s);
        s = fmaf(qv[2], x.z, s); s = fmaf(qv[3], x.w, s);
        s = fmaf(qv[4], y.x, s); s = fmaf(qv[5], y.y, s);
        s = fmaf(qv[6], y.z, s); s = fmaf(qv[7], y.w, s);
        #pragma unroll
        for (int off = 32; off >= 1; off >>= 1) s += __shfl_xor(s, off, 64);
        if (lane == 0) a.sc[k] = s * 0.0441941738241592f;  // 1/sqrt(512)
    }
    __syncthreads();

    if (w == 0) {
        float s = a.sc[lane];
        float m = s;
        #pragma unroll
        for (int off = 32; off >= 1; off >>= 1) m = fmaxf(m, __shfl_xor(m, off, 64));
        const float e = __expf(s - m);
        float sum = e;
        #pragma unroll
        for (int off = 32; off >= 1; off >>= 1) sum += __shfl_xor(sum, off, 64);
        a.sc[lane] = e / sum;
    }
    __syncthreads();

    float a0 = 0.f, a1 = 0.f;
    const int d2 = t * 2;
    #pragma unroll 8
    for (int k = 0; k < 64; ++k) {
        const float ak = a.sc[k];
        const float2 u = *(const float2*)(entW + (size_t)a.tails[k] * 512 + d2);
        a0 = fmaf(ak, u.x, a0);
        a1 = fmaf(ak, u.y, a1);
    }
    ((float2*)(agg + (size_t)n * 512))[t] = make_float2(a0, a1);
}

__global__ __launch_bounds__(256, 1) void mega_kernel(
    const float* __restrict__ drugW, const float* __restrict__ relaW,
    const float* __restrict__ entW, const float* __restrict__ Wa,
    const float* __restrict__ linW, const float* __restrict__ linb,
    const float* __restrict__ gamma, const float* __restrict__ beta,
    const int* __restrict__ drug_name, const int* __restrict__ adj_tail,
    const int* __restrict__ adj_rel, const int* __restrict__ nbr_idx,
    const int* __restrict__ nbr_deg, const int* __restrict__ epoch,
    int skq, int skh, int* cnt, float* q, float* agg, float* hbuf,
    float* __restrict__ out)
{
    __shared__ SmemU sm;
    const int blk = blockIdx.x;
    const int t = threadIdx.x;

    // ---- stage 1: q = drugE @ Wa (split-K skq) ----
    for (int job = blk; job < 72 * skq; job += NBLK) {
        const int bz = job / 72, rem = job % 72;
        gemm_tile(sm.g, drugW, drug_name, q /*unused*/, Wa, q,
                  N_DRUG, 512 / skq, 0, rem % 8, rem / 8, bz);
    }
    gridbar(cnt, 0);

    // ---- stage 2: attention ----
    for (int n = blk; n < N_DRUG; n += NBLK)
        attn_one(sm.a, relaW, entW, adj_tail, adj_rel, q, skq, agg, n);
    gridbar(cnt, 1);

    // ---- stage 3: h = [agg|drugE] @ linW (split-K skh) ----
    for (int job = blk; job < 72 * skh; job += NBLK) {
        const int bz = job / 72, rem = job % 72;
        gemm_tile(sm.g, drugW, drug_name, agg, linW, hbuf,
                  N_DRUG, 1024 / skh, 1, rem % 8, rem / 8, bz);
    }
    gridbar(cnt, 2);

    // ---- stage 4: fused splitK-sum + bias + relu + BN + smoothing scan ----
    if (blk >= 64) return;
    __syncthreads();
    {
        ScanS& S = sm.s;
        const int c8 = t & 7;          // col within 8-col stripe
        const int rr = t >> 3;         // staging row group 0..31
        const int h  = (t >> 3) & 1;   // neighbor half (rounds)
        const int j  = t >> 4;         // node slot 0..15 (rounds)
        const int c0 = blk * 8;

        // phase 0a: padded u16 neighbor table, mxs(+1), inv
        for (int i = t; i < N_DRUG; i += 256) {
            const int d = nbr_deg[i];
            S.inv[i] = (d > 0) ? 0.5f / (float)d : 0.f;
            const int4* np = (const int4*)&nbr_idx[i * MAXDEG];
            unsigned* op = (unsigned*)&S.offs[i * MAXDEG];
            int mx = -1;
            #pragma unroll
            for (int u = 0; u < 8; ++u) {
                int4 qq = np[u];
                const int b = u * 4;
                qq.x = (b + 0 < d) ? qq.x : N_DRUG;
                qq.y = (b + 1 < d) ? qq.y : N_DRUG;
                qq.z = (b + 2 < d) ? qq.z : N_DRUG;
                qq.w = (b + 3 < d) ? qq.w : N_DRUG;
                mx = max(mx, (qq.x < i) ? qq.x : -1);
                mx = max(mx, (qq.y < i) ? qq.y : -1);
                mx = max(mx, (qq.z < i) ? qq.z : -1);
                mx = max(mx, (qq.w < i) ? qq.w : -1);
                op[2 * u]     = (unsigned)(qq.x & 0xffff) | ((unsigned)qq.y << 16);
                op[2 * u + 1] = (unsigned)(qq.z & 0xffff) | ((unsigned)qq.w << 16);
            }
            S.mxs[i] = (unsigned short)(mx + 1);
        }
        // phase 0b: stage fs = relu(sum partials + bias), partial stats
        {
            const float bb = linb[c0 + c8];
            float sl = 0.f, ql = 0.f;
            for (int r = rr; r < N_DRUG; r += 32) {
                const float* hp = hbuf + (size_t)r * DIM + c0 + c8;
                float v = hp[0];
                for (int pt = 1; pt < skh; ++pt) v += hp[(size_t)pt * MN];
                v = fmaxf(v + bb, 0.f);
                S.fs[r * FSW + c8] = v;
                sl += v;
                ql = fmaf(v, v, ql);
            }
            S.part[0][rr][c8] = sl;
            S.part[1][rr][c8] = ql;
        }
        if (t < FSW) S.fs[N_DRUG * FSW + t] = 0.f;
        __syncthreads();

        // phase 1: BN finalize (t<8) || first group boundary (wave 3)
        if (t < 8) {
            float s = 0.f, sq = 0.f;
            #pragma unroll
            for (int k = 0; k < 32; ++k) { s += S.part[0][k][t]; sq += S.part[1][k][t]; }
            const float mean = s * (1.f / N_DRUG);
            const float var = sq * (1.f / N_DRUG) - mean * mean;
            const float rstd = rsqrtf(var + 1e-5f);
            const float scl = gamma[c0 + t] * rstd;
            S.bnp[0][t] = scl;
            S.bnp[1][t] = beta[c0 + t] - mean * scl;
        }
        if ((t >> 6) == 3) {
            const int l = t & 63;
            const int jj = 1 + l;
            const bool flag = (l >= 15) || (jj >= N_DRUG) ||
                              ((int)S.mxs[min(jj, N_DRUG - 1)] > 0);
            const unsigned long long b = __ballot(flag) & 0xFFFFULL;
            if (l == 0) S.ge0 = 1 + (int)__builtin_ctzll(b);
        }
        __syncthreads();

        // phase 2: BN apply
        {
            const float scl = S.bnp[0][c8];
            const float shf = S.bnp[1][c8];
            for (int r = rr; r < N_DRUG; r += 32)
                S.fs[r * FSW + c8] = fmaf(S.fs[r * FSW + c8], scl, shf);
        }
        __syncthreads();

        // rounds
        if (epoch[0] > 1) {
            int gs = 0, ge = S.ge0, par = 0;
            uint4 ca, cb;
            {
                const uint4* p = (const uint4*)&S.offs[min(j, N_DRUG - 1) * MAXDEG + h * 16];
                ca = p[0]; cb = p[1];
            }
            while (gs < N_DRUG) {
                const bool pred = (gs + j) < ge;
                float sh = 0.f;
                if (pred) {
                    float s0 = 0.f, s1 = 0.f, s2 = 0.f, s3 = 0.f;
#define G2(W) { s0 += S.fs[(W & 0xffffu) * FSW + c8]; s1 += S.fs[(W >> 16) * FSW + c8]; }
#define G4(Q) { G2(Q.x) unsigned w2_##Q = 0; (void)w2_##Q; }
                    G2(ca.x) G2(ca.y); s2 += 0.f; s3 += 0.f;
                    G2(ca.z) G2(ca.w)
                    G2(cb.x) G2(cb.y)
                    G2(cb.z) G2(cb.w)
#undef G4
#undef G2
                    sh = (s0 + s1) + (s2 + s3);
                }
                // prefetch next group's offsets
                uint4 na, nb;
                {
                    const uint4* p = (const uint4*)&S.offs[min(ge + j, N_DRUG - 1) * MAXDEG + h * 16];
                    na = p[0]; nb = p[1];
                }
                float nv = 0.f;
                if (pred) {
                    const float cur = S.fs[(gs + j) * FSW + c8];
                    const float iv = S.inv[gs + j];
                    const float wg = (iv == 0.f) ? 1.f : 0.5f;
                    float sx = sh + __shfl_xor(sh, 8, 64);
                    nv = fmaf(sx, iv, cur * wg);
                }
                if ((t >> 6) == 3) {
                    const int l = t & 63;
                    const int jj = ge + 1 + l;
                    const bool flag = (l >= 15) || (jj >= N_DRUG) ||
                                      ((int)S.mxs[min(jj, N_DRUG - 1)] > ge);
                    const unsigned long long b = __ballot(flag) & 0xFFFFULL;
                    if (l == 0) S.genext[par] = ge + 1 + (int)__builtin_ctzll(b);
                }
                __syncthreads();   // reads done before writes
                if (pred && h == 0) S.fs[(gs + j) * FSW + c8] = nv;
                __syncthreads();   // writes + genext visible
                gs = ge;
                ge = S.genext[par];
                par ^= 1;
                ca = na; cb = nb;
            }
        }
        __syncthreads();

        for (int r = rr; r < N_DRUG; r += 32)
            out[(size_t)r * DIM + c0 + c8] = S.fs[r * FSW + c8];
    }
}

extern "C" void kernel_launch(void* const* d_in, const int* in_sizes, int n_in,
                              void* d_out, int out_size, void* d_ws, size_t ws_size,
                              hipStream_t stream)
{
    const float* drugW = (const float*)d_in[0];
    const float* relaW = (const float*)d_in[1];
    const float* entW  = (const float*)d_in[2];
    const float* Wa    = (const float*)d_in[3];
    const float* linW  = (const float*)d_in[4];
    const float* linb  = (const float*)d_in[5];
    const float* gamma = (const float*)d_in[6];
    const float* beta  = (const float*)d_in[7];
    const int* drug_name = (const int*)d_in[8];
    const int* adj_tail  = (const int*)d_in[9];
    const int* adj_rel   = (const int*)d_in[10];
    const int* nbr_idx   = (const int*)d_in[11];
    const int* nbr_deg   = (const int*)d_in[12];
    const int* epoch     = (const int*)d_in[13];

    int* cnt = (int*)d_ws;
    float* base = (float*)d_ws + 16;
    const bool big = ws_size >= (size_t)(7 * MN + 16) * sizeof(float);
    const int skq = big ? 2 : 1;
    const int skh = big ? 4 : 2;
    float* q   = base;
    float* agg = q + (size_t)skq * MN;
    float* hb  = agg + (size_t)MN;
    float* out = (float*)d_out;

    hipMemsetAsync(d_ws, 0, 64, stream);   // zero barrier counters (capture-safe node)
    mega_kernel<<<NBLK, 256, 0, stream>>>(
        drugW, relaW, entW, Wa, linW, linb, gamma, beta,
        drug_name, adj_tail, adj_rel, nbr_idx, nbr_deg, epoch,
        skq, skh, cnt, q, agg, hb, out);
}

// Round 8
// 262.199 us; speedup vs baseline: 1.2739x; 1.2739x over previous
//
#include <hip/hip_runtime.h>

#define N_DRUG 572
#define DIM 512
#define MAXDEG 32
#define FS 17            // scan LDS stride: 16 cols + 1 pad

// ---------------------------------------------------------------------------
// fwd_kernel: per-drug fused  q = drugE@Wa -> attention -> agg -> h = cat@linW
// 286 blocks x 256 threads; block b handles drugs n0=2b, n0+1.
// All intermediates in LDS; weights streamed row-coalesced (L2-resident).
// ---------------------------------------------------------------------------
__global__ __launch_bounds__(256) void fwd_kernel(
    const float* __restrict__ drugW, const float* __restrict__ relaW,
    const float* __restrict__ entW, const float* __restrict__ Wa,
    const float* __restrict__ linW, const float* __restrict__ linb,
    const int* __restrict__ drug_name, const int* __restrict__ adj_tail,
    const int* __restrict__ adj_rel, float* __restrict__ out)
{
    __shared__ float2 ci[1024];     // k<512: (agg0,agg1)[k] ; k>=512: (de0,de1)[k-512]
    __shared__ float  qs[2][512];   // q per drug
    __shared__ float  at[2][64];    // scores -> attn weights
    __shared__ int    tails[2][64];
    __shared__ int    rels[2][64];

    const int t  = threadIdx.x;
    const int n0 = blockIdx.x * 2;

    // ---- phase 1: stage drug_e pair into ci[512..1023]; load adj tables ----
    {
        const int r0 = drug_name[n0];
        const int r1 = drug_name[n0 + 1];
        const float2 v0 = *(const float2*)(drugW + (size_t)r0 * 512 + 2 * t);
        const float2 v1 = *(const float2*)(drugW + (size_t)r1 * 512 + 2 * t);
        ci[512 + 2 * t]     = make_float2(v0.x, v1.x);
        ci[512 + 2 * t + 1] = make_float2(v0.y, v1.y);
    }
    if (t < 128) {
        const int d = t >> 6, kk = t & 63;
        tails[d][kk] = adj_tail[(n0 + d) * 64 + kk];
        rels[d][kk]  = adj_rel[(n0 + d) * 64 + kk];
    }
    __syncthreads();

    // ---- phase 2: q (both drugs), thread t owns cols 2t, 2t+1 ----
    {
        float q00 = 0.f, q01 = 0.f, q10 = 0.f, q11 = 0.f;
        const float* wp = Wa + 2 * t;
        for (int k0 = 0; k0 < 512; k0 += 8) {
            float2 w[8];
            #pragma unroll
            for (int u = 0; u < 8; ++u)
                w[u] = *(const float2*)(wp + (size_t)(k0 + u) * 512);
            #pragma unroll
            for (int u = 0; u < 8; ++u) {
                const float2 dd = ci[512 + k0 + u];   // LDS broadcast
                q00 = fmaf(dd.x, w[u].x, q00); q01 = fmaf(dd.x, w[u].y, q01);
                q10 = fmaf(dd.y, w[u].x, q10); q11 = fmaf(dd.y, w[u].y, q11);
            }
        }
        qs[0][2 * t] = q00; qs[0][2 * t + 1] = q01;
        qs[1][2 * t] = q10; qs[1][2 * t + 1] = q11;
    }
    __syncthreads();

    // ---- phase 3: scores (wave w: drug w>>1, score-half w&1) ----
    {
        const int w = t >> 6, lane = t & 63;
        const int d = w >> 1;
        float qv[8];
        {
            const float4* qp = (const float4*)&qs[d][lane * 8];
            const float4 x = qp[0], y = qp[1];
            qv[0]=x.x; qv[1]=x.y; qv[2]=x.z; qv[3]=x.w;
            qv[4]=y.x; qv[5]=y.y; qv[6]=y.z; qv[7]=y.w;
        }
        #pragma unroll 4
        for (int kk = 0; kk < 32; ++kk) {
            const int k = (w & 1) * 32 + kk;
            const float4* p = (const float4*)(relaW + (size_t)rels[d][k] * 512 + lane * 8);
            const float4 x = p[0], y = p[1];
            float s = 0.f;
            s = fmaf(qv[0], x.x, s); s = fmaf(qv[1], x.y, s);
            s = fmaf(qv[2], x.z, s); s = fmaf(qv[3], x.w, s);
            s = fmaf(qv[4], y.x, s); s = fmaf(qv[5], y.y, s);
            s = fmaf(qv[6], y.z, s); s = fmaf(qv[7], y.w, s);
            #pragma unroll
            for (int off = 32; off >= 1; off >>= 1) s += __shfl_xor(s, off, 64);
            if (lane == 0) at[d][k] = s * 0.0441941738241592f;  // 1/sqrt(512)
        }
    }
    __syncthreads();

    // ---- softmax per drug (waves 0 and 2) ----
    {
        const int w = t >> 6, lane = t & 63;
        if ((w & 1) == 0) {
            const int d = w >> 1;
            const float s = at[d][lane];
            float m = s;
            #pragma unroll
            for (int off = 32; off >= 1; off >>= 1) m = fmaxf(m, __shfl_xor(m, off, 64));
            const float e = __expf(s - m);
            float sum = e;
            #pragma unroll
            for (int off = 32; off >= 1; off >>= 1) sum += __shfl_xor(sum, off, 64);
            at[d][lane] = e / sum;
        }
    }
    __syncthreads();

    // ---- phase 4: agg gather (128 threads per drug, float4 cols) ----
    {
        const int d = t >> 7;
        const int c4 = (t & 127) * 4;
        float a0 = 0.f, a1 = 0.f, a2 = 0.f, a3 = 0.f;
        #pragma unroll 8
        for (int k = 0; k < 64; ++k) {
            const float ak = at[d][k];
            const float4 e = *(const float4*)(entW + (size_t)tails[d][k] * 512 + c4);
            a0 = fmaf(ak, e.x, a0); a1 = fmaf(ak, e.y, a1);
            a2 = fmaf(ak, e.z, a2); a3 = fmaf(ak, e.w, a3);
        }
        float* cw = (float*)ci;   // component d of ci[c4+i]
        cw[2 * (c4 + 0) + d] = a0;
        cw[2 * (c4 + 1) + d] = a1;
        cw[2 * (c4 + 2) + d] = a2;
        cw[2 * (c4 + 3) + d] = a3;
    }
    __syncthreads();

    // ---- phase 5: h = [agg|de] @ linW + bias, ReLU; write both rows ----
    {
        float h00 = 0.f, h01 = 0.f, h10 = 0.f, h11 = 0.f;
        const float* wp = linW + 2 * t;
        for (int k0 = 0; k0 < 1024; k0 += 8) {
            float2 w[8];
            #pragma unroll
            for (int u = 0; u < 8; ++u)
                w[u] = *(const float2*)(wp + (size_t)(k0 + u) * 512);
            #pragma unroll
            for (int u = 0; u < 8; ++u) {
                const float2 dd = ci[k0 + u];   // LDS broadcast
                h00 = fmaf(dd.x, w[u].x, h00); h01 = fmaf(dd.x, w[u].y, h01);
                h10 = fmaf(dd.y, w[u].x, h10); h11 = fmaf(dd.y, w[u].y, h11);
            }
        }
        const float2 bb = *(const float2*)(linb + 2 * t);
        h00 = fmaxf(h00 + bb.x, 0.f); h01 = fmaxf(h01 + bb.y, 0.f);
        h10 = fmaxf(h10 + bb.x, 0.f); h11 = fmaxf(h11 + bb.y, 0.f);
        *(float2*)(out + (size_t)n0 * 512 + 2 * t)       = make_float2(h00, h01);
        *(float2*)(out + (size_t)(n0 + 1) * 512 + 2 * t) = make_float2(h10, h11);
    }
}

// ---------------------------------------------------------------------------
// Fused BN + sequential smoothing scan (round-6 version, staging simplified:
// h in `hout` is already bias+ReLU'd). 32 blocks x 16 cols, 512 threads.
// ---------------------------------------------------------------------------
__global__ __launch_bounds__(512) void scan_kernel(
    float* hout, const float* __restrict__ gamma, const float* __restrict__ beta,
    const int* __restrict__ nbr_idx, const int* __restrict__ nbr_deg,
    const int* __restrict__ epoch)
{
    __shared__ float fs[(N_DRUG + 1) * FS];      // row N_DRUG = zeros (dummy)
    __shared__ int   offs[N_DRUG * MAXDEG];      // padded neighbor rows (dummy=N_DRUG)
    __shared__ float2 ivw[N_DRUG];               // (0.5/deg, 0.5) or (0,1)
    __shared__ int   mxs[N_DRUG];                // max lower-dep row, -1 if none
    __shared__ float part[2][32][16];            // stats partials
    __shared__ float bnp[2][16];                 // scl, shf per col
    __shared__ int   genext[2];
    __shared__ int   ge0s;

    const int t  = threadIdx.x;
    const int c  = t & 15;
    const int h  = (t >> 4) & 1;
    const int j  = t >> 5;         // node slot 0..15
    const int rr = t >> 4;         // staging row-group 0..31
    const int c0 = blockIdx.x * 16;

    // ---- phase 0a: neighbor table (padded), mx, ivw ----
    for (int i = t; i < N_DRUG; i += 512) {
        const int d = nbr_deg[i];
        ivw[i] = (d > 0) ? make_float2(0.5f / (float)d, 0.5f) : make_float2(0.f, 1.f);
        const int4* np = (const int4*)&nbr_idx[i * MAXDEG];
        int4* op = (int4*)&offs[i * MAXDEG];
        int mx = -1;
        #pragma unroll
        for (int u = 0; u < 8; ++u) {
            int4 qq = np[u];
            const int b = u * 4;
            qq.x = (b + 0 < d) ? qq.x : N_DRUG;
            qq.y = (b + 1 < d) ? qq.y : N_DRUG;
            qq.z = (b + 2 < d) ? qq.z : N_DRUG;
            qq.w = (b + 3 < d) ? qq.w : N_DRUG;
            mx = max(mx, (qq.x < i) ? qq.x : -1);
            mx = max(mx, (qq.y < i) ? qq.y : -1);
            mx = max(mx, (qq.z < i) ? qq.z : -1);
            mx = max(mx, (qq.w < i) ? qq.w : -1);
            op[u] = qq;
        }
        mxs[i] = mx;
    }

    // ---- phase 0b: stage fs (already bias+ReLU'd); partial stats ----
    {
        float sl = 0.f, ql = 0.f;
        for (int r = rr; r < N_DRUG; r += 32) {
            const float v = hout[(size_t)r * DIM + c0 + c];
            fs[r * FS + c] = v;
            sl += v;
            ql = fmaf(v, v, ql);
        }
        part[0][rr][c] = sl;
        part[1][rr][c] = ql;
    }
    if (t < FS) fs[N_DRUG * FS + t] = 0.f;
    __syncthreads();

    // ---- phase 1: stats finalize (t<16) || first group boundary (wave 7) ----
    if (t < 16) {
        float s = 0.f, sq = 0.f;
        #pragma unroll
        for (int k = 0; k < 32; ++k) { s += part[0][k][t]; sq += part[1][k][t]; }
        const float mean = s * (1.f / N_DRUG);
        const float var = sq * (1.f / N_DRUG) - mean * mean;
        const float rstd = rsqrtf(var + 1e-5f);
        const float scl = gamma[c0 + t] * rstd;
        bnp[0][t] = scl;
        bnp[1][t] = beta[c0 + t] - mean * scl;
    }
    if ((t >> 6) == 7) {
        const int l = t & 63;
        const int jj = 1 + l;
        const bool flag = (l >= 15) || (jj >= N_DRUG) || (mxs[min(jj, N_DRUG - 1)] >= 0);
        const unsigned long long b = __ballot(flag) & 0xFFFFULL;
        if (l == 0) ge0s = 1 + (int)__builtin_ctzll(b);
    }
    __syncthreads();

    // ---- phase 2: BN apply ----
    {
        const float scl = bnp[0][c];
        const float shf = bnp[1][c];
        for (int r = rr; r < N_DRUG; r += 32)
            fs[r * FS + c] = fmaf(fs[r * FS + c], scl, shf);
    }
    __syncthreads();

    // ---- rounds ----
    if (epoch[0] > 1) {
        int gs = 0, ge = ge0s;
        int4 o0, o1, o2, o3;
        {
            const int4* p = (const int4*)&offs[min(j, N_DRUG - 1) * MAXDEG + h * 16];
            o0 = p[0]; o1 = p[1]; o2 = p[2]; o3 = p[3];
        }
        int par = 0;
        while (gs < N_DRUG) {
            const bool pred = (gs + j) < ge;
            float s0 = 0.f, s1 = 0.f, s2 = 0.f, s3 = 0.f;
#define GATH4(Q) { s0 += fs[Q.x * FS + c]; s1 += fs[Q.y * FS + c]; \
                   s2 += fs[Q.z * FS + c]; s3 += fs[Q.w * FS + c]; }
            if (pred) { GATH4(o0) GATH4(o1) GATH4(o2) GATH4(o3) }
#undef GATH4
            int4 n0, n1, n2, n3;
            {
                const int4* p = (const int4*)&offs[min(ge + j, N_DRUG - 1) * MAXDEG + h * 16];
                n0 = p[0]; n1 = p[1]; n2 = p[2]; n3 = p[3];
            }
            float nv = 0.f;
            if (pred) {
                const float cur = fs[(gs + j) * FS + c];
                const float2 iw = ivw[gs + j];
                float sh = (s0 + s1) + (s2 + s3);
                sh += __shfl_xor(sh, 16, 64);    // combine the two halves
                nv = fmaf(sh, iw.x, cur * iw.y);
            }
            if ((t >> 6) == 7) {
                const int l = t & 63;
                const int jj = ge + 1 + l;
                const bool flag = (l >= 15) || (jj >= N_DRUG) ||
                                  (mxs[min(jj, N_DRUG - 1)] >= ge);
                const unsigned long long b = __ballot(flag) & 0xFFFFULL;
                if (l == 0) genext[par] = ge + 1 + (int)__builtin_ctzll(b);
            }
            __syncthreads();   // all reads done before any write (anti-deps)
            if (pred && h == 0) fs[(gs + j) * FS + c] = nv;
            __syncthreads();   // writes + genext visible
            gs = ge;
            ge = genext[par];
            par ^= 1;
            o0 = n0; o1 = n1; o2 = n2; o3 = n3;
        }
    }
    __syncthreads();

    // ---- write back ----
    for (int r = rr; r < N_DRUG; r += 32)
        hout[(size_t)r * DIM + c0 + c] = fs[r * FS + c];
}

extern "C" void kernel_launch(void* const* d_in, const int* in_sizes, int n_in,
                              void* d_out, int out_size, void* d_ws, size_t ws_size,
                              hipStream_t stream)
{
    const float* drugW = (const float*)d_in[0];
    const float* relaW = (const float*)d_in[1];
    const float* entW  = (const float*)d_in[2];
    const float* Wa    = (const float*)d_in[3];
    const float* linW  = (const float*)d_in[4];
    const float* linb  = (const float*)d_in[5];
    const float* gamma = (const float*)d_in[6];
    const float* beta  = (const float*)d_in[7];
    const int* drug_name = (const int*)d_in[8];
    const int* adj_tail  = (const int*)d_in[9];
    const int* adj_rel   = (const int*)d_in[10];
    const int* nbr_idx   = (const int*)d_in[11];
    const int* nbr_deg   = (const int*)d_in[12];
    const int* epoch     = (const int*)d_in[13];

    float* out = (float*)d_out;    // h lives in d_out; scan updates in place

    fwd_kernel<<<N_DRUG / 2, 256, 0, stream>>>(
        drugW, relaW, entW, Wa, linW, linb, drug_name, adj_tail, adj_rel, out);
    scan_kernel<<<32, 512, 0, stream>>>(
        out, gamma, beta, nbr_idx, nbr_deg, epoch);
}

// Round 9
// 202.586 us; speedup vs baseline: 1.6488x; 1.2943x over previous
//
#include <hip/hip_runtime.h>

#define N_DRUG 572
#define DIM 512
#define MAXDEG 32
#define FS 17            // scan LDS stride: 16 cols + 1 pad

// ---------------------------------------------------------------------------
// fwd_kernel: fused q = drugE@Wa -> attention -> agg -> h = [agg|de]@linW
// 143 blocks x 512 threads; block b handles drugs 4b..4b+3.
// Split-K 4-way on both matmuls; per-drug input planes in LDS (broadcast
// reads); float4 weight streams, coalesced 1KB/wave/row.
// ---------------------------------------------------------------------------
__global__ __launch_bounds__(512) void fwd_kernel(
    const float* __restrict__ drugW, const float* __restrict__ relaW,
    const float* __restrict__ entW, const float* __restrict__ Wa,
    const float* __restrict__ linW, const float* __restrict__ linb,
    const int* __restrict__ drug_name, const int* __restrict__ adj_tail,
    const int* __restrict__ adj_rel, float* __restrict__ out)
{
    __shared__ float cin[4][1024];    // [d][k]: k<512 agg, k>=512 drug_e
    __shared__ float red[4][4][512];  // [kh][d][col] split-K partials
    __shared__ float qs[4][512];      // q per drug
    __shared__ float at[4][64];       // scores -> attn weights
    __shared__ int   tails[4][64];
    __shared__ int   rels[4][64];

    const int t  = threadIdx.x;
    const int n0 = blockIdx.x * 4;
    const int c4 = (t & 127) * 4;     // col quad
    const int kh = t >> 7;            // k quarter 0..3

    // ---- stage drug_e planes + adjacency ----
    #pragma unroll
    for (int d = 0; d < 4; ++d) {
        const int rd = drug_name[n0 + d];
        cin[d][512 + t] = drugW[(size_t)rd * 512 + t];
    }
    if (t < 256) {
        const int d = t >> 6, kk = t & 63;
        tails[d][kk] = adj_tail[(n0 + d) * 64 + kk];
        rels[d][kk]  = adj_rel[(n0 + d) * 64 + kk];
    }
    __syncthreads();

    // ---- phase 2: q = drug_e @ Wa (split-K 4, 128 k each) ----
    {
        float acc[4][4] = {{0.f}};     // [d][col_i]
        const float* wp = Wa + (size_t)(kh * 128) * 512 + c4;
        const int kb = 512 + kh * 128;
        for (int k0 = 0; k0 < 128; k0 += 4) {
            const float4 w0 = *(const float4*)(wp + (size_t)(k0 + 0) * 512);
            const float4 w1 = *(const float4*)(wp + (size_t)(k0 + 1) * 512);
            const float4 w2 = *(const float4*)(wp + (size_t)(k0 + 2) * 512);
            const float4 w3 = *(const float4*)(wp + (size_t)(k0 + 3) * 512);
            const float4 ww[4] = {w0, w1, w2, w3};
            #pragma unroll
            for (int u = 0; u < 4; ++u) {
                const float4 w = ww[u];
                #pragma unroll
                for (int d = 0; d < 4; ++d) {
                    const float b = cin[d][kb + k0 + u];   // wave-uniform bcast
                    acc[d][0] = fmaf(b, w.x, acc[d][0]);
                    acc[d][1] = fmaf(b, w.y, acc[d][1]);
                    acc[d][2] = fmaf(b, w.z, acc[d][2]);
                    acc[d][3] = fmaf(b, w.w, acc[d][3]);
                }
            }
        }
        #pragma unroll
        for (int d = 0; d < 4; ++d)
            *(float4*)&red[kh][d][c4] = make_float4(acc[d][0], acc[d][1], acc[d][2], acc[d][3]);
    }
    __syncthreads();
    #pragma unroll
    for (int d = 0; d < 4; ++d)
        qs[d][t] = red[0][d][t] + red[1][d][t] + red[2][d][t] + red[3][d][t];
    __syncthreads();

    // ---- phase 3: scores (wave w: drug w>>1, 32-score half w&1) ----
    {
        const int w = t >> 6, lane = t & 63;
        const int d = w >> 1;
        float qv[8];
        {
            const float4* qp = (const float4*)&qs[d][lane * 8];
            const float4 x = qp[0], y = qp[1];
            qv[0]=x.x; qv[1]=x.y; qv[2]=x.z; qv[3]=x.w;
            qv[4]=y.x; qv[5]=y.y; qv[6]=y.z; qv[7]=y.w;
        }
        #pragma unroll 4
        for (int kk = 0; kk < 32; ++kk) {
            const int k = (w & 1) * 32 + kk;
            const float4* p = (const float4*)(relaW + (size_t)rels[d][k] * 512 + lane * 8);
            const float4 x = p[0], y = p[1];
            float s = 0.f;
            s = fmaf(qv[0], x.x, s); s = fmaf(qv[1], x.y, s);
            s = fmaf(qv[2], x.z, s); s = fmaf(qv[3], x.w, s);
            s = fmaf(qv[4], y.x, s); s = fmaf(qv[5], y.y, s);
            s = fmaf(qv[6], y.z, s); s = fmaf(qv[7], y.w, s);
            #pragma unroll
            for (int off = 32; off >= 1; off >>= 1) s += __shfl_xor(s, off, 64);
            if (lane == 0) at[d][k] = s * 0.0441941738241592f;  // 1/sqrt(512)
        }
    }
    __syncthreads();

    // ---- softmax per drug (waves 0,2,4,6) ----
    {
        const int w = t >> 6, lane = t & 63;
        if ((w & 1) == 0) {
            const int d = w >> 1;
            const float s = at[d][lane];
            float m = s;
            #pragma unroll
            for (int off = 32; off >= 1; off >>= 1) m = fmaxf(m, __shfl_xor(m, off, 64));
            const float e = __expf(s - m);
            float sum = e;
            #pragma unroll
            for (int off = 32; off >= 1; off >>= 1) sum += __shfl_xor(sum, off, 64);
            at[d][lane] = e / sum;
        }
    }
    __syncthreads();

    // ---- phase 4: agg gather (drug = t>>7, col quad = (t&127)*4) ----
    {
        const int d = t >> 7;
        const int cg = (t & 127) * 4;
        float a0 = 0.f, a1 = 0.f, a2 = 0.f, a3 = 0.f;
        #pragma unroll 8
        for (int k = 0; k < 64; ++k) {
            const float ak = at[d][k];
            const float4 e = *(const float4*)(entW + (size_t)tails[d][k] * 512 + cg);
            a0 = fmaf(ak, e.x, a0); a1 = fmaf(ak, e.y, a1);
            a2 = fmaf(ak, e.z, a2); a3 = fmaf(ak, e.w, a3);
        }
        *(float4*)&cin[d][cg] = make_float4(a0, a1, a2, a3);   // conflict-free b128
    }
    __syncthreads();

    // ---- phase 5: h = [agg|de] @ linW (split-K 4, 256 k each) ----
    {
        float acc[4][4] = {{0.f}};
        const int kb = kh * 256;
        const float* wp = linW + (size_t)kb * 512 + c4;
        for (int k0 = 0; k0 < 256; k0 += 4) {
            const float4 w0 = *(const float4*)(wp + (size_t)(k0 + 0) * 512);
            const float4 w1 = *(const float4*)(wp + (size_t)(k0 + 1) * 512);
            const float4 w2 = *(const float4*)(wp + (size_t)(k0 + 2) * 512);
            const float4 w3 = *(const float4*)(wp + (size_t)(k0 + 3) * 512);
            const float4 ww[4] = {w0, w1, w2, w3};
            #pragma unroll
            for (int u = 0; u < 4; ++u) {
                const float4 w = ww[u];
                #pragma unroll
                for (int d = 0; d < 4; ++d) {
                    const float b = cin[d][kb + k0 + u];
                    acc[d][0] = fmaf(b, w.x, acc[d][0]);
                    acc[d][1] = fmaf(b, w.y, acc[d][1]);
                    acc[d][2] = fmaf(b, w.z, acc[d][2]);
                    acc[d][3] = fmaf(b, w.w, acc[d][3]);
                }
            }
        }
        #pragma unroll
        for (int d = 0; d < 4; ++d)
            *(float4*)&red[kh][d][c4] = make_float4(acc[d][0], acc[d][1], acc[d][2], acc[d][3]);
    }
    __syncthreads();
    {
        const float bb = linb[t];
        #pragma unroll
        for (int d = 0; d < 4; ++d) {
            const float v = red[0][d][t] + red[1][d][t] + red[2][d][t] + red[3][d][t] + bb;
            out[(size_t)(n0 + d) * 512 + t] = fmaxf(v, 0.f);
        }
    }
}

// ---------------------------------------------------------------------------
// Fused BN + sequential smoothing scan. 32 blocks x 16 cols, 512 threads.
// u16 neighbor offsets PRE-SCALED by FS (row*17 <= 9724 fits u16):
// prefetch = 2 x b128 per thread; gathers use the index directly.
// ---------------------------------------------------------------------------
__global__ __launch_bounds__(512) void scan_kernel(
    float* hout, const float* __restrict__ gamma, const float* __restrict__ beta,
    const int* __restrict__ nbr_idx, const int* __restrict__ nbr_deg,
    const int* __restrict__ epoch)
{
    __shared__ float fs[(N_DRUG + 1) * FS];      // row N_DRUG = zeros (dummy)
    __shared__ alignas(16) unsigned short offs[N_DRUG * MAXDEG];  // row*FS, dummy=N_DRUG*FS
    __shared__ float2 ivw[N_DRUG];               // (0.5/deg, 0.5) or (0,1)
    __shared__ int   mxs[N_DRUG];                // max lower-dep row, -1 if none
    __shared__ float part[2][32][16];
    __shared__ float bnp[2][16];
    __shared__ int   genext[2];
    __shared__ int   ge0s;

    const int t  = threadIdx.x;
    const int c  = t & 15;
    const int h  = (t >> 4) & 1;
    const int j  = t >> 5;         // node slot 0..15
    const int rr = t >> 4;         // staging row-group 0..31
    const int c0 = blockIdx.x * 16;

    // ---- phase 0a: padded, pre-scaled u16 neighbor table; mx; ivw ----
    for (int i = t; i < N_DRUG; i += 512) {
        const int d = nbr_deg[i];
        ivw[i] = (d > 0) ? make_float2(0.5f / (float)d, 0.5f) : make_float2(0.f, 1.f);
        const int4* np = (const int4*)&nbr_idx[i * MAXDEG];
        unsigned* op = (unsigned*)&offs[i * MAXDEG];
        int mx = -1;
        #pragma unroll
        for (int u = 0; u < 8; ++u) {
            int4 qq = np[u];
            const int b = u * 4;
            qq.x = (b + 0 < d) ? qq.x : N_DRUG;
            qq.y = (b + 1 < d) ? qq.y : N_DRUG;
            qq.z = (b + 2 < d) ? qq.z : N_DRUG;
            qq.w = (b + 3 < d) ? qq.w : N_DRUG;
            mx = max(mx, (qq.x < i) ? qq.x : -1);
            mx = max(mx, (qq.y < i) ? qq.y : -1);
            mx = max(mx, (qq.z < i) ? qq.z : -1);
            mx = max(mx, (qq.w < i) ? qq.w : -1);
            op[2 * u]     = (unsigned)(qq.x * FS) | ((unsigned)(qq.y * FS) << 16);
            op[2 * u + 1] = (unsigned)(qq.z * FS) | ((unsigned)(qq.w * FS) << 16);
        }
        mxs[i] = mx;
    }

    // ---- phase 0b: stage fs (already bias+ReLU'd); partial stats ----
    {
        float sl = 0.f, ql = 0.f;
        for (int r = rr; r < N_DRUG; r += 32) {
            const float v = hout[(size_t)r * DIM + c0 + c];
            fs[r * FS + c] = v;
            sl += v;
            ql = fmaf(v, v, ql);
        }
        part[0][rr][c] = sl;
        part[1][rr][c] = ql;
    }
    if (t < FS) fs[N_DRUG * FS + t] = 0.f;
    __syncthreads();

    // ---- phase 1: stats finalize (t<16) || first group boundary (wave 7) ----
    if (t < 16) {
        float s = 0.f, sq = 0.f;
        #pragma unroll
        for (int k = 0; k < 32; ++k) { s += part[0][k][t]; sq += part[1][k][t]; }
        const float mean = s * (1.f / N_DRUG);
        const float var = sq * (1.f / N_DRUG) - mean * mean;
        const float rstd = rsqrtf(var + 1e-5f);
        const float scl = gamma[c0 + t] * rstd;
        bnp[0][t] = scl;
        bnp[1][t] = beta[c0 + t] - mean * scl;
    }
    if ((t >> 6) == 7) {
        const int l = t & 63;
        const int jj = 1 + l;
        const bool flag = (l >= 15) || (jj >= N_DRUG) || (mxs[min(jj, N_DRUG - 1)] >= 0);
        const unsigned long long b = __ballot(flag) & 0xFFFFULL;
        if (l == 0) ge0s = 1 + (int)__builtin_ctzll(b);
    }
    __syncthreads();

    // ---- phase 2: BN apply ----
    {
        const float scl = bnp[0][c];
        const float shf = bnp[1][c];
        for (int r = rr; r < N_DRUG; r += 32)
            fs[r * FS + c] = fmaf(fs[r * FS + c], scl, shf);
    }
    __syncthreads();

    // ---- rounds ----
    if (epoch[0] > 1) {
        int gs = 0, ge = ge0s;
        uint4 ca, cb;
        {
            const uint4* p = (const uint4*)&offs[min(j, N_DRUG - 1) * MAXDEG + h * 16];
            ca = p[0]; cb = p[1];
        }
        int par = 0;
        while (gs < N_DRUG) {
            const bool pred = (gs + j) < ge;
            float s0 = 0.f, s1 = 0.f;
#define G2(W) { s0 += fs[(W & 0xffffu) + c]; s1 += fs[(W >> 16) + c]; }
            if (pred) { G2(ca.x) G2(ca.y) G2(ca.z) G2(ca.w)
                        G2(cb.x) G2(cb.y) G2(cb.z) G2(cb.w) }
#undef G2
            uint4 na, nb;
            {
                const uint4* p = (const uint4*)&offs[min(ge + j, N_DRUG - 1) * MAXDEG + h * 16];
                na = p[0]; nb = p[1];
            }
            float nv = 0.f;
            if (pred) {
                const float cur = fs[(gs + j) * FS + c];
                const float2 iw = ivw[gs + j];
                float sh = s0 + s1;
                sh += __shfl_xor(sh, 16, 64);    // combine the two halves
                nv = fmaf(sh, iw.x, cur * iw.y);
            }
            if ((t >> 6) == 7) {
                const int l = t & 63;
                const int jj = ge + 1 + l;
                const bool flag = (l >= 15) || (jj >= N_DRUG) ||
                                  (mxs[min(jj, N_DRUG - 1)] >= ge);
                const unsigned long long b = __ballot(flag) & 0xFFFFULL;
                if (l == 0) genext[par] = ge + 1 + (int)__builtin_ctzll(b);
            }
            __syncthreads();   // all reads done before any write (anti-deps)
            if (pred && h == 0) fs[(gs + j) * FS + c] = nv;
            __syncthreads();   // writes + genext visible
            gs = ge;
            ge = genext[par];
            par ^= 1;
            ca = na; cb = nb;
        }
    }
    __syncthreads();

    // ---- write back ----
    for (int r = rr; r < N_DRUG; r += 32)
        hout[(size_t)r * DIM + c0 + c] = fs[r * FS + c];
}

extern "C" void kernel_launch(void* const* d_in, const int* in_sizes, int n_in,
                              void* d_out, int out_size, void* d_ws, size_t ws_size,
                              hipStream_t stream)
{
    const float* drugW = (const float*)d_in[0];
    const float* relaW = (const float*)d_in[1];
    const float* entW  = (const float*)d_in[2];
    const float* Wa    = (const float*)d_in[3];
    const float* linW  = (const float*)d_in[4];
    const float* linb  = (const float*)d_in[5];
    const float* gamma = (const float*)d_in[6];
    const float* beta  = (const float*)d_in[7];
    const int* drug_name = (const int*)d_in[8];
    const int* adj_tail  = (const int*)d_in[9];
    const int* adj_rel   = (const int*)d_in[10];
    const int* nbr_idx   = (const int*)d_in[11];
    const int* nbr_deg   = (const int*)d_in[12];
    const int* epoch     = (const int*)d_in[13];

    float* out = (float*)d_out;    // h lives in d_out; scan updates in place

    fwd_kernel<<<N_DRUG / 4, 512, 0, stream>>>(
        drugW, relaW, entW, Wa, linW, linb, drug_name, adj_tail, adj_rel, out);
    scan_kernel<<<32, 512, 0, stream>>>(
        out, gamma, beta, nbr_idx, nbr_deg, epoch);
}